// Round 14
// baseline (196.258 us; speedup 1.0000x reference)
//
#include <hip/hip_runtime.h>
#include <math.h>

#define NB 32768
#define H 320
#define V 34
#define N4 1280            // 4*H
#define BM 128
#define BN 128
#define KSTEPS 10          // K chunks of 32 (storage tiling)
#define NWIN 5             // K-loop windows of BK=64 (2 chunks)
#define NWG ((NB / BM) * (N4 / BN))   // 2560

typedef _Float16 f16;
typedef f16 f16x4 __attribute__((ext_vector_type(4)));
typedef f16 f16x8 __attribute__((ext_vector_type(8)));
typedef float f32x4 __attribute__((ext_vector_type(4)));

// ws layout (bytes):
//   [0)          floats: gtp [V][N4] (43520), jb2 [V] @54400
//   [217744)     Bt1/Bt2: K-tiled LANE-LINEAR fp16 planes of gate-permuted W_hh
//                Bt1 = fp16(w), Bt2 = fp16((w - w1)*2048)
//   [1856144)    Jp1/Jp2: K-tiled lane-linear fp16 planes of [joint_W | C2] (48 rows)
// lane-linear within 16x32 subtile: elem(row,k) -> (k>>3)*128 + (row&15)*8 + (k&7)
// single-acc algebra: acc = A1*B1 + (A1*2^-11)*Bt2 + At2*B1   (3-pass, PROVEN)
// A operand: fp32 h loaded directly (8 contiguous floats/lane), split in-register
#define WS_GTP 0
#define WS_JB2 54400
#define WS_B_BYTE 217744
#define BT_COUNT (N4 * H)          // 409600 per plane
#define WS_JP_BYTE 1856144
#define JP_COUNT (48 * 640)        // 30720 per plane

// joint GEMM geometry
#define JBM 64
#define JBK 32
#define JKSTEPS 20                 // 640 / 32

// prep grid sections (h-split section removed: split fused into GEMM)
#define PREP_P2 50                 // Bt: (ks,n) threads = 12800
#define PREP_P0 170                // gtp: 43520
#define PREP_P3 120                // Jp (+C2 fold): 30720
#define PREP_NWG (PREP_P2 + PREP_P0 + PREP_P3 + 1)   // 341

__device__ __forceinline__ float sigf(float x) {
    return 1.0f / (1.0f + __expf(-x));
}
__device__ __forceinline__ float tanh_fast(float x) {
    return 1.0f - 2.0f / (1.0f + __expf(2.0f * x));
}

typedef const __attribute__((address_space(1))) unsigned int* gas_t;
typedef __attribute__((address_space(3))) unsigned int* las_t;

__device__ __forceinline__ void split8(const float* e, f16x8& p1, f16x8& p2) {
    #pragma unroll
    for (int j = 0; j < 8; ++j) {
        f16 a = (f16)e[j];
        p1[j] = a;
        p2[j] = (f16)((e[j] - (float)a) * 2048.0f);
    }
}

// in-register fp32 -> (hi, true-residual) split — identical math to prior prep
__device__ __forceinline__ void cvt_split(const float4& v0, const float4& v1,
                                          f16x8& p1, f16x8& p2) {
    float e[8] = {v0.x, v0.y, v0.z, v0.w, v1.x, v1.y, v1.z, v1.w};
    #pragma unroll
    for (int j = 0; j < 8; ++j) {
        f16 a = (f16)e[j];
        p1[j] = a;
        p2[j] = (f16)(e[j] - (float)a);
    }
}

// ---------------- fused preprocessing: one launch (small) ------------------
__global__ void prep(const float* __restrict__ embed_W,
                     const float* __restrict__ W_ih,
                     const float* __restrict__ b_ih,
                     const float* __restrict__ b_hh,
                     const float* __restrict__ pred_W,
                     const float* __restrict__ pred_b,
                     const float* __restrict__ joint_W,
                     const float* __restrict__ joint_b,
                     const float* __restrict__ W_hh,
                     float* __restrict__ ws) {
    const int bid = blockIdx.x;
    const int t = threadIdx.x;
    if (bid < PREP_P2) {
        // gate-permuted W_hh -> Bt planes, K-tiled lane-linear. thread = (ks, n)
        int id = bid * 256 + t;
        int ks = id / 1280, n = id - ks * 1280;
        int orig = (n & 3) * H + (n >> 2);
        const float* src = W_hh + (size_t)orig * H + ks * 32;
        f16* bt1 = (f16*)((char*)ws + WS_B_BYTE);
        f16* bt2 = bt1 + BT_COUNT;
        size_t tbase = ((size_t)(n >> 7) * KSTEPS + ks) * 4096
                       + ((n & 127) >> 4) * 512 + (n & 15) * 8;
        #pragma unroll
        for (int g = 0; g < 4; ++g) {
            float4 v0 = *(const float4*)(src + g * 8);
            float4 v1 = *(const float4*)(src + g * 8 + 4);
            float e[8] = {v0.x, v0.y, v0.z, v0.w, v1.x, v1.y, v1.z, v1.w};
            f16x8 p1, p2;
            split8(e, p1, p2);
            *(f16x8*)(bt1 + tbase + g * 128) = p1;
            *(f16x8*)(bt2 + tbase + g * 128) = p2;
        }
    } else if (bid < PREP_P2 + PREP_P0) {
        // permuted gate table gtp[v][n] = b_ih+b_hh+embed_W[v]·W_ih[orig]
        int id = (bid - PREP_P2) * 256 + t;
        int v = id / N4, n = id % N4;
        int orig = (n & 3) * H + (n >> 2);
        float acc = b_ih[orig] + b_hh[orig];
        const float* e = embed_W + (size_t)v * H;
        const float* w = W_ih + (size_t)orig * H;
        for (int k = 0; k < H; k += 4) {
            float4 e4 = *(const float4*)(e + k);
            float4 w4 = *(const float4*)(w + k);
            acc = fmaf(e4.x, w4.x, acc);
            acc = fmaf(e4.y, w4.y, acc);
            acc = fmaf(e4.z, w4.z, acc);
            acc = fmaf(e4.w, w4.w, acc);
        }
        ws[WS_GTP + id] = acc;
    } else if (bid < PREP_P2 + PREP_P0 + PREP_P3) {
        // Jp planes of [joint_W | C2], 48 rows (34 real), K-tiled lane-linear.
        int id = (bid - PREP_P2 - PREP_P0) * 256 + t;
        int n = id / 640, k = id % 640;
        float wv = 0.0f;
        if (n < V) {
            if (k < H) {
                wv = joint_W[(size_t)n * H + k];
            } else {
                float acc = 0.0f;
                const float* jw = joint_W + (size_t)n * H;
                for (int j = 0; j < H; ++j)
                    acc = fmaf(jw[j], pred_W[(size_t)j * H + (k - H)], acc);
                wv = acc;
            }
        }
        f16 w1 = (f16)wv;
        f16 w2 = (f16)((wv - (float)w1) * 2048.0f);
        int kk = k & 31;
        int off = (k >> 5) * 1536 + (n >> 4) * 512 + (kk >> 3) * 128
                  + (n & 15) * 8 + (kk & 7);
        f16* jp1 = (f16*)((char*)ws + WS_JP_BYTE);
        jp1[off] = w1;
        jp1[JP_COUNT + off] = w2;
    } else {
        // jb2[v] = joint_b[v] + joint_W[v]·pred_b
        if (t < V) {
            float acc = joint_b[t];
            const float* jw = joint_W + (size_t)t * H;
            for (int j = 0; j < H; ++j)
                acc = fmaf(jw[j], pred_b[j], acc);
            ws[WS_JB2 + t] = acc;
        }
    }
}

// ---- main GEMM: BK=64 windows, A from fp32 h (in-register split),
//      B 2x32KB LDS dbuf, c prefetched at entry, full-tile epilogue ----
__launch_bounds__(256, 2)
__global__ void lstm_gemm_fast(const int* __restrict__ x,
                               const float* __restrict__ h_in,
                               const float* __restrict__ c_in,
                               const float* __restrict__ ws,
                               float* __restrict__ out) {
    __shared__ __align__(16) char smem[65536];
    const int tid = threadIdx.x, lane = tid & 63, w = tid >> 6;

    int l = (blockIdx.x & 7) * (NWG / 8) + (blockIdx.x >> 3);  // XCD chunks
    const int mb = l / (N4 / BN);   // n-fastest: h panel L2-resident across nb
    const int nb = l % (N4 / BN);
    const int m0 = mb * BM, n0 = nb * BN;

    const f16* Bt1 = (const f16*)((const char*)ws + WS_B_BYTE);
    const f16* Bt2 = Bt1 + BT_COUNT;
    const float* gtp = ws + WS_GTP;
    float* hn_out = out + NB;
    float* cn_out = out + NB + (size_t)NB * H;

    const int asub = (w >> 1) * 4;   // A subtile base (rows wm..wm+63)
    const int bsub = (w & 1) * 4;    // B subtile base
    const int lo = lane * 8;         // lane-linear fragment offset (f16)

    // per-lane fp32 A row pointers: lane holds row (subtile + lane&15),
    // k-chunk (lane>>4)*8 .. +7 — 8 contiguous floats per fragment
    const float* hrow[4];
    #pragma unroll
    for (int mi = 0; mi < 4; ++mi)
        hrow[mi] = h_in + (size_t)(m0 + (asub + mi) * 16 + (lane & 15)) * H
                   + (lane >> 4) * 8;

    // stage B kstep-pair T into buffer parity: 32KB, 8 global_load_lds per wave
    auto stageB = [&](int T, int parity) {
        const f16* srcp = (w < 2) ? Bt1 : Bt2;
        const int p = (w < 2) ? 0 : 1;
        #pragma unroll
        for (int ksl = 0; ksl < 2; ++ksl) {
            const f16* src = srcp + (size_t)(nb * KSTEPS + 2 * T + ksl) * 4096
                             + (w & 1) * 2048;
            char* dst = smem + parity * 32768 + p * 16384 + ksl * 8192
                        + (w & 1) * 4096;
            #pragma unroll
            for (int i = 0; i < 4; ++i) {
                __builtin_amdgcn_global_load_lds(
                    (gas_t)(const void*)(src + i * 512 + lane * 8),
                    (las_t)(void*)(dst + i * 1024), 16, 0, 0);
            }
        }
    };

    f32x4 acc[4][4];
    #pragma unroll
    for (int i = 0; i < 4; ++i)
        #pragma unroll
        for (int j = 0; j < 4; ++j)
            acc[i][j] = (f32x4){0.f, 0.f, 0.f, 0.f};

    stageB(0, 0);
    __syncthreads();

    // prefetch c for the epilogue: 16 scalar loads, latency hidden by K-loop
    const int hk0 = n0 >> 2;
    float cpre[16];
    #pragma unroll
    for (int it = 0; it < 16; ++it)
        cpre[it] = c_in[(size_t)(m0 + it * 8 + (tid >> 5)) * H + hk0 + (tid & 31)];

    #pragma unroll
    for (int T = 0; T < NWIN; ++T) {
        const int par = T & 1;
        const f16* B1 = (const f16*)(smem + par * 32768);
        const f16* B2 = B1 + 8192;

        // --- K-half 0: b frags + fp32 A loads ---
        f16x8 b1a[4], b2a[4];
        #pragma unroll
        for (int nj = 0; nj < 4; ++nj) {
            b1a[nj] = *(const f16x8*)(B1 + (bsub + nj) * 512 + lo);
            b2a[nj] = *(const f16x8*)(B2 + (bsub + nj) * 512 + lo);
        }
        float4 av0[4], av1[4];
        #pragma unroll
        for (int mi = 0; mi < 4; ++mi) {
            av0[mi] = *(const float4*)(hrow[mi] + (2 * T) * 32);
            av1[mi] = *(const float4*)(hrow[mi] + (2 * T) * 32 + 4);
        }
        if (T < NWIN - 1) stageB(T + 1, par ^ 1);

        // in-register split (bit-identical to prior prep path)
        f16x8 a1a[4], a2a[4];
        #pragma unroll
        for (int mi = 0; mi < 4; ++mi)
            cvt_split(av0[mi], av1[mi], a1a[mi], a2a[mi]);

        // ksl0 pass1: A1*B1
        __builtin_amdgcn_s_setprio(1);
        #pragma unroll
        for (int mi = 0; mi < 4; ++mi)
            #pragma unroll
            for (int nj = 0; nj < 4; ++nj)
                acc[mi][nj] = __builtin_amdgcn_mfma_f32_16x16x32_f16(
                    a1a[mi], b1a[nj], acc[mi][nj], 0, 0, 0);
        __builtin_amdgcn_s_setprio(0);
        #pragma unroll
        for (int mi = 0; mi < 4; ++mi)
            #pragma unroll
            for (int j = 0; j < 8; ++j)
                a1a[mi][j] = a1a[mi][j] * (f16)0.00048828125f;
        // issue fp32 A loads for K-half 1 (consumed ~1000 cyc later)
        float4 cv0[4], cv1[4];
        #pragma unroll
        for (int mi = 0; mi < 4; ++mi) {
            cv0[mi] = *(const float4*)(hrow[mi] + (2 * T + 1) * 32);
            cv1[mi] = *(const float4*)(hrow[mi] + (2 * T + 1) * 32 + 4);
        }
        __builtin_amdgcn_s_setprio(1);
        // ksl0 pass2: (A1*2^-11)*Bt2
        #pragma unroll
        for (int mi = 0; mi < 4; ++mi)
            #pragma unroll
            for (int nj = 0; nj < 4; ++nj)
                acc[mi][nj] = __builtin_amdgcn_mfma_f32_16x16x32_f16(
                    a1a[mi], b2a[nj], acc[mi][nj], 0, 0, 0);
        // ksl0 pass3: (h-h1)*B1
        #pragma unroll
        for (int mi = 0; mi < 4; ++mi)
            #pragma unroll
            for (int nj = 0; nj < 4; ++nj)
                acc[mi][nj] = __builtin_amdgcn_mfma_f32_16x16x32_f16(
                    a2a[mi], b1a[nj], acc[mi][nj], 0, 0, 0);
        __builtin_amdgcn_s_setprio(0);

        // --- K-half 1: b frags + convert ---
        f16x8 b1c[4], b2c[4];
        #pragma unroll
        for (int nj = 0; nj < 4; ++nj) {
            b1c[nj] = *(const f16x8*)(B1 + 4096 + (bsub + nj) * 512 + lo);
            b2c[nj] = *(const f16x8*)(B2 + 4096 + (bsub + nj) * 512 + lo);
        }
        f16x8 a1c[4], a2c[4];
        #pragma unroll
        for (int mi = 0; mi < 4; ++mi)
            cvt_split(cv0[mi], cv1[mi], a1c[mi], a2c[mi]);

        __builtin_amdgcn_s_setprio(1);
        #pragma unroll
        for (int mi = 0; mi < 4; ++mi)
            #pragma unroll
            for (int nj = 0; nj < 4; ++nj)
                acc[mi][nj] = __builtin_amdgcn_mfma_f32_16x16x32_f16(
                    a1c[mi], b1c[nj], acc[mi][nj], 0, 0, 0);
        __builtin_amdgcn_s_setprio(0);
        #pragma unroll
        for (int mi = 0; mi < 4; ++mi)
            #pragma unroll
            for (int j = 0; j < 8; ++j)
                a1c[mi][j] = a1c[mi][j] * (f16)0.00048828125f;
        __builtin_amdgcn_s_setprio(1);
        #pragma unroll
        for (int mi = 0; mi < 4; ++mi)
            #pragma unroll
            for (int nj = 0; nj < 4; ++nj)
                acc[mi][nj] = __builtin_amdgcn_mfma_f32_16x16x32_f16(
                    a1c[mi], b2c[nj], acc[mi][nj], 0, 0, 0);
        #pragma unroll
        for (int mi = 0; mi < 4; ++mi)
            #pragma unroll
            for (int nj = 0; nj < 4; ++nj)
                acc[mi][nj] = __builtin_amdgcn_mfma_f32_16x16x32_f16(
                    a2c[mi], b1c[nj], acc[mi][nj], 0, 0, 0);
        __builtin_amdgcn_s_setprio(0);

        __syncthreads();   // stage(T+1) issued a full window ago -> drain free
    }

    // epilogue: full [128][128] gates in 64KB LDS, XOR word-swizzle
    const int wm = (w >> 1) * 64, wn = (w & 1) * 64;
    float* gates = (float*)smem;
    #pragma unroll
    for (int mi = 0; mi < 4; ++mi)
        #pragma unroll
        for (int nj = 0; nj < 4; ++nj) {
            f32x4 v = acc[mi][nj];
            int n = wn + nj * 16 + (lane & 15);
            int r0 = wm + mi * 16 + (lane >> 4) * 4;
            #pragma unroll
            for (int q = 0; q < 4; ++q) {
                int row = r0 + q;
                gates[row * 128 + (n ^ ((row & 7) << 2))] = v[q];
            }
        }
    __syncthreads();

    // LSTM cell + coalesced writes: 4096 outputs = 128 m x 32 hk
    #pragma unroll
    for (int it = 0; it < 16; ++it) {
        int ml = it * 8 + (tid >> 5), hkl = tid & 31;
        int k0s = (ml & 7) << 2;
        f32x4 g4 = *(const f32x4*)&gates[ml * 128 + ((hkl * 4) ^ k0s)];
        int m = m0 + ml;
        int hk = hk0 + hkl;
        int xv = x[m];
        float4 b4 = *(const float4*)(gtp + (size_t)xv * N4 + n0 + hkl * 4);
        float ig = sigf(g4[0] + b4.x);
        float fg = sigf(g4[1] + b4.y);
        float gg = tanh_fast(g4[2] + b4.z);
        float og = sigf(g4[3] + b4.w);
        float cn = fmaf(fg, cpre[it], ig * gg);
        float hn = og * tanh_fast(cn);
        hn_out[(size_t)m * H + hk] = hn;
        cn_out[(size_t)m * H + hk] = cn;
    }
}

// joint + argmax MFMA GEMM: logits = [enc | hn] @ [joint_W | C2]^T
__launch_bounds__(256, 2)
__global__ void joint_argmax(const float* __restrict__ enc,
                             const float* __restrict__ ws,
                             float* __restrict__ out) {
    // per buffer: A1[2048] A2[2048] B1[1536] B2[1536] halves = 14336 B
    __shared__ __align__(16) char smem[28672];
    const int tid = threadIdx.x, lane = tid & 63, w = tid >> 6;
    const int m0 = blockIdx.x * JBM;

    const f16* Jp1 = (const f16*)((const char*)ws + WS_JP_BYTE);
    const f16* Jp2 = Jp1 + JP_COUNT;
    const float* hn = out + NB;
    const float* jb2 = ws + WS_JB2;

    f16* base = (f16*)smem;

    f32x4 accM[3], accC[3];
    #pragma unroll
    for (int j = 0; j < 3; ++j) {
        accM[j] = (f32x4){0.f, 0.f, 0.f, 0.f};
        accC[j] = (f32x4){0.f, 0.f, 0.f, 0.f};
    }

    // A: one lane-linear 16B chunk per thread; B: linear 3KB copy
    auto stage = [&](int t, f16* A1, f16* A2, f16* B1, f16* B2) {
        const float* srcp = (t < 10) ? enc : hn;
        const int koff = (t % 10) * JBK;
        int row = (tid >> 6) * 16 + (tid & 15);
        int k0 = ((tid & 63) >> 4) * 8;
        const float* sp = srcp + (size_t)(m0 + row) * H + koff + k0;
        float4 v0 = *(const float4*)sp;
        float4 v1 = *(const float4*)(sp + 4);
        float e[8] = {v0.x, v0.y, v0.z, v0.w, v1.x, v1.y, v1.z, v1.w};
        f16x8 p1, p2;
        split8(e, p1, p2);
        *(f16x8*)(A1 + tid * 8) = p1;
        *(f16x8*)(A2 + tid * 8) = p2;
        if (tid < 192) {
            *(int4*)(B1 + tid * 8) = *(const int4*)(Jp1 + t * 1536 + tid * 8);
            *(int4*)(B2 + tid * 8) = *(const int4*)(Jp2 + t * 1536 + tid * 8);
        }
    };

    stage(0, base, base + 2048, base + 4096, base + 5632);
    __syncthreads();

    const int lo = lane * 8;
    int cur = 0;
    for (int t = 0; t < JKSTEPS; ++t) {
        if (t < JKSTEPS - 1) {
            f16* nb_ = base + (cur ^ 1) * 7168;
            stage(t + 1, nb_, nb_ + 2048, nb_ + 4096, nb_ + 5632);
        }
        f16* A1 = base + cur * 7168;
        f16* A2 = A1 + 2048;
        f16* B1 = A1 + 4096;
        f16* B2 = A1 + 5632;

        f16x8 a1 = *(const f16x8*)(A1 + w * 512 + lo);
        f16x8 a2 = *(const f16x8*)(A2 + w * 512 + lo);
        f16x8 b1[3], b2[3];
        #pragma unroll
        for (int nj = 0; nj < 3; ++nj) {
            b1[nj] = *(const f16x8*)(B1 + nj * 512 + lo);
            b2[nj] = *(const f16x8*)(B2 + nj * 512 + lo);
        }
        #pragma unroll
        for (int nj = 0; nj < 3; ++nj) {
            accM[nj] = __builtin_amdgcn_mfma_f32_16x16x32_f16(a1, b1[nj], accM[nj], 0, 0, 0);
            accC[nj] = __builtin_amdgcn_mfma_f32_16x16x32_f16(a1, b2[nj], accC[nj], 0, 0, 0);
            accC[nj] = __builtin_amdgcn_mfma_f32_16x16x32_f16(a2, b1[nj], accC[nj], 0, 0, 0);
        }
        __syncthreads();
        cur ^= 1;
    }

    // merge -> logits LDS [64][49] (stride 49: conflict-free column reads)
    float* lg = (float*)smem;
    const int wm = w * 16;
    #pragma unroll
    for (int nj = 0; nj < 3; ++nj) {
        int n = nj * 16 + (lane & 15);
        int mr = wm + (lane >> 4) * 4;
        #pragma unroll
        for (int q = 0; q < 4; ++q)
            lg[(mr + q) * 49 + n] = fmaf(accC[nj][q], 1.0f / 2048.0f, accM[nj][q]);
    }
    __syncthreads();

    // argmax per row (numpy: first max wins -> strict >)
    if (tid < JBM) {
        const float* row = lg + tid * 49;
        float best = row[0] + jb2[0];
        int bi = 0;
        #pragma unroll
        for (int v = 1; v < V; ++v) {
            float t2 = row[v] + jb2[v];
            if (t2 > best) { best = t2; bi = v; }
        }
        out[m0 + tid] = (float)bi;
    }
}

extern "C" void kernel_launch(void* const* d_in, const int* in_sizes, int n_in,
                              void* d_out, int out_size, void* d_ws, size_t ws_size,
                              hipStream_t stream) {
    const int*   x       = (const int*)  d_in[0];
    const float* enc     = (const float*)d_in[1];
    const float* h       = (const float*)d_in[2];
    const float* c       = (const float*)d_in[3];
    const float* embed_W = (const float*)d_in[4];
    const float* W_ih    = (const float*)d_in[5];
    const float* W_hh    = (const float*)d_in[6];
    const float* b_ih    = (const float*)d_in[7];
    const float* b_hh    = (const float*)d_in[8];
    const float* pred_W  = (const float*)d_in[9];
    const float* pred_b  = (const float*)d_in[10];
    const float* joint_W = (const float*)d_in[11];
    const float* joint_b = (const float*)d_in[12];
    float* out = (float*)d_out;
    float* ws  = (float*)d_ws;

    prep<<<PREP_NWG, 256, 0, stream>>>(embed_W, W_ih, b_ih, b_hh,
                                       pred_W, pred_b, joint_W, joint_b,
                                       W_hh, ws);
    lstm_gemm_fast<<<NWG, 256, 0, stream>>>(x, h, c, ws, out);
    joint_argmax<<<NB / JBM, 256, 0, stream>>>(enc, ws, out);
}

// Round 15
// 159.201 us; speedup vs baseline: 1.2328x; 1.2328x over previous
//
#include <hip/hip_runtime.h>
#include <math.h>

#define NB 32768
#define H 320
#define V 34
#define N4 1280            // 4*H
#define BM 128
#define BN 128
#define KSTEPS 10          // K chunks of 32 (storage tiling)
#define NWIN 5             // K-loop windows of BK=64 (2 chunks)
#define NWG ((NB / BM) * (N4 / BN))   // 2560

typedef _Float16 f16;
typedef f16 f16x4 __attribute__((ext_vector_type(4)));
typedef f16 f16x8 __attribute__((ext_vector_type(8)));
typedef float f32x4 __attribute__((ext_vector_type(4)));

// ws layout (bytes):
//   [0)          floats: gtp [V][N4] (43520), jb2 [V] @54400
//   [217744)     Bt1/Bt2: K-tiled LANE-LINEAR fp16 planes of gate-permuted W_hh
//                Bt1 = fp16(w), Bt2 = fp16((w - w1)*2048)
//   [1856144)    Jp1/Jp2: K-tiled lane-linear fp16 planes of [joint_W | C2] (48 rows)
//   [1979136)    At1/At2: K-tiled lane-linear fp16 planes of h
//                At1 = fp16(h), At2 = fp16(h - h1)  (TRUE residual)
// lane-linear within 16x32 subtile: elem(row,k) -> (k>>3)*128 + (row&15)*8 + (k&7)
// single-acc algebra: acc = A1*B1 + (A1*2^-11)*Bt2 + At2*B1   (3-pass, PROVEN)
#define WS_GTP 0
#define WS_JB2 54400
#define WS_B_BYTE 217744
#define BT_COUNT (N4 * H)          // 409600 per plane
#define WS_JP_BYTE 1856144
#define JP_COUNT (48 * 640)        // 30720 per plane
#define WS_AT_BYTE 1979136
#define AT_COUNT (NB * H)          // 10485760 per plane

// joint GEMM geometry
#define JBM 64
#define JBK 32
#define JKSTEPS 20                 // 640 / 32

// prep grid sections
#define PREP_P4 1280               // split h: (ks,m) threads = 327680
#define PREP_P2 50                 // Bt: (ks,n) threads = 12800
#define PREP_P0 170                // gtp: 43520
#define PREP_P3 120                // Jp (+C2 fold): 30720
#define PREP_NWG (PREP_P4 + PREP_P2 + PREP_P0 + PREP_P3 + 1)   // 1621

__device__ __forceinline__ float sigf(float x) {
    return 1.0f / (1.0f + __expf(-x));
}
__device__ __forceinline__ float tanh_fast(float x) {
    return 1.0f - 2.0f / (1.0f + __expf(2.0f * x));
}

typedef const __attribute__((address_space(1))) unsigned int* gas_t;
typedef __attribute__((address_space(3))) unsigned int* las_t;

__device__ __forceinline__ void split8(const float* e, f16x8& p1, f16x8& p2) {
    #pragma unroll
    for (int j = 0; j < 8; ++j) {
        f16 a = (f16)e[j];
        p1[j] = a;
        p2[j] = (f16)((e[j] - (float)a) * 2048.0f);
    }
}

__device__ __forceinline__ void split8_res(const float* e, f16x8& p1, f16x8& p2) {
    #pragma unroll
    for (int j = 0; j < 8; ++j) {
        f16 a = (f16)e[j];
        p1[j] = a;
        p2[j] = (f16)(e[j] - (float)a);   // true residual, no scale
    }
}

// ---------------- fused preprocessing: one launch --------------------------
__global__ void prep(const float* __restrict__ embed_W,
                     const float* __restrict__ W_ih,
                     const float* __restrict__ b_ih,
                     const float* __restrict__ b_hh,
                     const float* __restrict__ pred_W,
                     const float* __restrict__ pred_b,
                     const float* __restrict__ joint_W,
                     const float* __restrict__ joint_b,
                     const float* __restrict__ W_hh,
                     const float* __restrict__ h_in,
                     float* __restrict__ ws) {
    const int bid = blockIdx.x;
    const int t = threadIdx.x;
    if (bid < PREP_P4) {
        // split h -> At planes, K-tiled lane-linear. thread = (ks, m)
        int id = bid * 256 + t;
        int ks = id >> 15, m = id & 32767;
        const float* src = h_in + (size_t)m * H + ks * 32;
        f16* at1 = (f16*)((char*)ws + WS_AT_BYTE);
        f16* at2 = at1 + AT_COUNT;
        size_t tbase = ((size_t)(m >> 7) * KSTEPS + ks) * 4096
                       + ((m & 127) >> 4) * 512 + (m & 15) * 8;
        #pragma unroll
        for (int g = 0; g < 4; ++g) {
            float4 v0 = *(const float4*)(src + g * 8);
            float4 v1 = *(const float4*)(src + g * 8 + 4);
            float e[8] = {v0.x, v0.y, v0.z, v0.w, v1.x, v1.y, v1.z, v1.w};
            f16x8 p1, p2;
            split8_res(e, p1, p2);
            *(f16x8*)(at1 + tbase + g * 128) = p1;
            *(f16x8*)(at2 + tbase + g * 128) = p2;
        }
    } else if (bid < PREP_P4 + PREP_P2) {
        // gate-permuted W_hh -> Bt planes, K-tiled lane-linear. thread = (ks, n)
        int id = (bid - PREP_P4) * 256 + t;
        int ks = id / 1280, n = id - ks * 1280;
        int orig = (n & 3) * H + (n >> 2);
        const float* src = W_hh + (size_t)orig * H + ks * 32;
        f16* bt1 = (f16*)((char*)ws + WS_B_BYTE);
        f16* bt2 = bt1 + BT_COUNT;
        size_t tbase = ((size_t)(n >> 7) * KSTEPS + ks) * 4096
                       + ((n & 127) >> 4) * 512 + (n & 15) * 8;
        #pragma unroll
        for (int g = 0; g < 4; ++g) {
            float4 v0 = *(const float4*)(src + g * 8);
            float4 v1 = *(const float4*)(src + g * 8 + 4);
            float e[8] = {v0.x, v0.y, v0.z, v0.w, v1.x, v1.y, v1.z, v1.w};
            f16x8 p1, p2;
            split8(e, p1, p2);
            *(f16x8*)(bt1 + tbase + g * 128) = p1;
            *(f16x8*)(bt2 + tbase + g * 128) = p2;
        }
    } else if (bid < PREP_P4 + PREP_P2 + PREP_P0) {
        // permuted gate table gtp[v][n] = b_ih+b_hh+embed_W[v]·W_ih[orig]
        int id = (bid - PREP_P4 - PREP_P2) * 256 + t;
        int v = id / N4, n = id % N4;
        int orig = (n & 3) * H + (n >> 2);
        float acc = b_ih[orig] + b_hh[orig];
        const float* e = embed_W + (size_t)v * H;
        const float* w = W_ih + (size_t)orig * H;
        for (int k = 0; k < H; k += 4) {
            float4 e4 = *(const float4*)(e + k);
            float4 w4 = *(const float4*)(w + k);
            acc = fmaf(e4.x, w4.x, acc);
            acc = fmaf(e4.y, w4.y, acc);
            acc = fmaf(e4.z, w4.z, acc);
            acc = fmaf(e4.w, w4.w, acc);
        }
        ws[WS_GTP + id] = acc;
    } else if (bid < PREP_P4 + PREP_P2 + PREP_P0 + PREP_P3) {
        // Jp planes of [joint_W | C2], 48 rows (34 real), K-tiled lane-linear.
        int id = (bid - PREP_P4 - PREP_P2 - PREP_P0) * 256 + t;
        int n = id / 640, k = id % 640;
        float wv = 0.0f;
        if (n < V) {
            if (k < H) {
                wv = joint_W[(size_t)n * H + k];
            } else {
                float acc = 0.0f;
                const float* jw = joint_W + (size_t)n * H;
                for (int j = 0; j < H; ++j)
                    acc = fmaf(jw[j], pred_W[(size_t)j * H + (k - H)], acc);
                wv = acc;
            }
        }
        f16 w1 = (f16)wv;
        f16 w2 = (f16)((wv - (float)w1) * 2048.0f);
        int kk = k & 31;
        int off = (k >> 5) * 1536 + (n >> 4) * 512 + (kk >> 3) * 128
                  + (n & 15) * 8 + (kk & 7);
        f16* jp1 = (f16*)((char*)ws + WS_JP_BYTE);
        jp1[off] = w1;
        jp1[JP_COUNT + off] = w2;
    } else {
        // jb2[v] = joint_b[v] + joint_W[v]·pred_b
        if (t < V) {
            float acc = joint_b[t];
            const float* jw = joint_W + (size_t)t * H;
            for (int j = 0; j < H; ++j)
                acc = fmaf(jw[j], pred_b[j], acc);
            ws[WS_JB2 + t] = acc;
        }
    }
}

// ---- main GEMM: BK=64 windows (5 barriers), A direct-from-global,
//      B 2x32KB LDS dbuf, c prefetched at entry, full-tile epilogue ----
__launch_bounds__(256, 2)
__global__ void lstm_gemm_fast(const int* __restrict__ x,
                               const float* __restrict__ c_in,
                               const float* __restrict__ ws,
                               float* __restrict__ out) {
    __shared__ __align__(16) char smem[65536];
    const int tid = threadIdx.x, lane = tid & 63, w = tid >> 6;

    int l = (blockIdx.x & 7) * (NWG / 8) + (blockIdx.x >> 3);  // XCD chunks
    const int mb = l / (N4 / BN);   // n-fastest: A panel L2-resident across nb
    const int nb = l % (N4 / BN);
    const int m0 = mb * BM, n0 = nb * BN;

    const f16* At1 = (const f16*)((const char*)ws + WS_AT_BYTE);
    const f16* At2 = At1 + AT_COUNT;
    const f16* Bt1 = (const f16*)((const char*)ws + WS_B_BYTE);
    const f16* Bt2 = Bt1 + BT_COUNT;
    const float* gtp = ws + WS_GTP;
    float* hn_out = out + NB;
    float* cn_out = out + NB + (size_t)NB * H;

    const int asub = (w >> 1) * 4;   // A subtile base (rows wm..wm+63)
    const int bsub = (w & 1) * 4;    // B subtile base
    const int lo = lane * 8;         // lane-linear fragment offset (f16)

    // stage B kstep-pair T into buffer parity: 32KB, 8 global_load_lds per wave
    auto stageB = [&](int T, int parity) {
        const f16* srcp = (w < 2) ? Bt1 : Bt2;
        const int p = (w < 2) ? 0 : 1;
        #pragma unroll
        for (int ksl = 0; ksl < 2; ++ksl) {
            const f16* src = srcp + (size_t)(nb * KSTEPS + 2 * T + ksl) * 4096
                             + (w & 1) * 2048;
            char* dst = smem + parity * 32768 + p * 16384 + ksl * 8192
                        + (w & 1) * 4096;
            #pragma unroll
            for (int i = 0; i < 4; ++i) {
                __builtin_amdgcn_global_load_lds(
                    (gas_t)(const void*)(src + i * 512 + lane * 8),
                    (las_t)(void*)(dst + i * 1024), 16, 0, 0);
            }
        }
    };

    f32x4 acc[4][4];
    #pragma unroll
    for (int i = 0; i < 4; ++i)
        #pragma unroll
        for (int j = 0; j < 4; ++j)
            acc[i][j] = (f32x4){0.f, 0.f, 0.f, 0.f};

    stageB(0, 0);
    __syncthreads();

    // prefetch c for the epilogue: 16 scalar loads, latency hidden by K-loop
    const int hk0 = n0 >> 2;
    float cpre[16];
    #pragma unroll
    for (int it = 0; it < 16; ++it)
        cpre[it] = c_in[(size_t)(m0 + it * 8 + (tid >> 5)) * H + hk0 + (tid & 31)];

    #pragma unroll
    for (int T = 0; T < NWIN; ++T) {
        const int par = T & 1;
        const f16* B1 = (const f16*)(smem + par * 32768);
        const f16* B2 = B1 + 8192;

        // --- K-half 0: b frags + a loads ---
        f16x8 b1a[4], b2a[4];
        #pragma unroll
        for (int nj = 0; nj < 4; ++nj) {
            b1a[nj] = *(const f16x8*)(B1 + (bsub + nj) * 512 + lo);
            b2a[nj] = *(const f16x8*)(B2 + (bsub + nj) * 512 + lo);
        }
        f16x8 a1a[4], a2a[4];
        {
            const f16* a1b = At1 + (size_t)(mb * KSTEPS + 2 * T) * 4096;
            const f16* a2b = At2 + (size_t)(mb * KSTEPS + 2 * T) * 4096;
            #pragma unroll
            for (int mi = 0; mi < 4; ++mi) {
                a1a[mi] = *(const f16x8*)(a1b + (asub + mi) * 512 + lo);
                a2a[mi] = *(const f16x8*)(a2b + (asub + mi) * 512 + lo);
            }
        }
        if (T < NWIN - 1) stageB(T + 1, par ^ 1);

        // ksl0 pass1: A1*B1
        __builtin_amdgcn_s_setprio(1);
        #pragma unroll
        for (int mi = 0; mi < 4; ++mi)
            #pragma unroll
            for (int nj = 0; nj < 4; ++nj)
                acc[mi][nj] = __builtin_amdgcn_mfma_f32_16x16x32_f16(
                    a1a[mi], b1a[nj], acc[mi][nj], 0, 0, 0);
        __builtin_amdgcn_s_setprio(0);
        #pragma unroll
        for (int mi = 0; mi < 4; ++mi)
            #pragma unroll
            for (int j = 0; j < 8; ++j)
                a1a[mi][j] = a1a[mi][j] * (f16)0.00048828125f;
        __builtin_amdgcn_s_setprio(1);
        // ksl0 pass2: (A1*2^-11)*Bt2
        #pragma unroll
        for (int mi = 0; mi < 4; ++mi)
            #pragma unroll
            for (int nj = 0; nj < 4; ++nj)
                acc[mi][nj] = __builtin_amdgcn_mfma_f32_16x16x32_f16(
                    a1a[mi], b2a[nj], acc[mi][nj], 0, 0, 0);
        __builtin_amdgcn_s_setprio(0);

        // issue K-half-1 A loads (consumed ~1000 cyc later)
        f16x8 a1c[4], a2c[4];
        {
            const f16* a1b = At1 + (size_t)(mb * KSTEPS + 2 * T + 1) * 4096;
            const f16* a2b = At2 + (size_t)(mb * KSTEPS + 2 * T + 1) * 4096;
            #pragma unroll
            for (int mi = 0; mi < 4; ++mi) {
                a1c[mi] = *(const f16x8*)(a1b + (asub + mi) * 512 + lo);
                a2c[mi] = *(const f16x8*)(a2b + (asub + mi) * 512 + lo);
            }
        }

        __builtin_amdgcn_s_setprio(1);
        // ksl0 pass3: (h-h1)*B1
        #pragma unroll
        for (int mi = 0; mi < 4; ++mi)
            #pragma unroll
            for (int nj = 0; nj < 4; ++nj)
                acc[mi][nj] = __builtin_amdgcn_mfma_f32_16x16x32_f16(
                    a2a[mi], b1a[nj], acc[mi][nj], 0, 0, 0);
        __builtin_amdgcn_s_setprio(0);

        // --- K-half 1: b frags ---
        f16x8 b1c[4], b2c[4];
        #pragma unroll
        for (int nj = 0; nj < 4; ++nj) {
            b1c[nj] = *(const f16x8*)(B1 + 4096 + (bsub + nj) * 512 + lo);
            b2c[nj] = *(const f16x8*)(B2 + 4096 + (bsub + nj) * 512 + lo);
        }
        __builtin_amdgcn_s_setprio(1);
        #pragma unroll
        for (int mi = 0; mi < 4; ++mi)
            #pragma unroll
            for (int nj = 0; nj < 4; ++nj)
                acc[mi][nj] = __builtin_amdgcn_mfma_f32_16x16x32_f16(
                    a1c[mi], b1c[nj], acc[mi][nj], 0, 0, 0);
        __builtin_amdgcn_s_setprio(0);
        #pragma unroll
        for (int mi = 0; mi < 4; ++mi)
            #pragma unroll
            for (int j = 0; j < 8; ++j)
                a1c[mi][j] = a1c[mi][j] * (f16)0.00048828125f;
        __builtin_amdgcn_s_setprio(1);
        #pragma unroll
        for (int mi = 0; mi < 4; ++mi)
            #pragma unroll
            for (int nj = 0; nj < 4; ++nj)
                acc[mi][nj] = __builtin_amdgcn_mfma_f32_16x16x32_f16(
                    a1c[mi], b2c[nj], acc[mi][nj], 0, 0, 0);
        #pragma unroll
        for (int mi = 0; mi < 4; ++mi)
            #pragma unroll
            for (int nj = 0; nj < 4; ++nj)
                acc[mi][nj] = __builtin_amdgcn_mfma_f32_16x16x32_f16(
                    a2c[mi], b1c[nj], acc[mi][nj], 0, 0, 0);
        __builtin_amdgcn_s_setprio(0);

        __syncthreads();   // stage(T+1) issued ~1900 cyc ago -> drain is free
    }

    // epilogue: full [128][128] gates in 64KB LDS, XOR word-swizzle
    const int wm = (w >> 1) * 64, wn = (w & 1) * 64;
    float* gates = (float*)smem;
    #pragma unroll
    for (int mi = 0; mi < 4; ++mi)
        #pragma unroll
        for (int nj = 0; nj < 4; ++nj) {
            f32x4 v = acc[mi][nj];
            int n = wn + nj * 16 + (lane & 15);
            int r0 = wm + mi * 16 + (lane >> 4) * 4;
            #pragma unroll
            for (int q = 0; q < 4; ++q) {
                int row = r0 + q;
                gates[row * 128 + (n ^ ((row & 7) << 2))] = v[q];
            }
        }
    __syncthreads();

    // LSTM cell + coalesced writes: 4096 outputs = 128 m x 32 hk
    #pragma unroll
    for (int it = 0; it < 16; ++it) {
        int ml = it * 8 + (tid >> 5), hkl = tid & 31;
        int k0s = (ml & 7) << 2;
        f32x4 g4 = *(const f32x4*)&gates[ml * 128 + ((hkl * 4) ^ k0s)];
        int m = m0 + ml;
        int hk = hk0 + hkl;
        int xv = x[m];
        float4 b4 = *(const float4*)(gtp + (size_t)xv * N4 + n0 + hkl * 4);
        float ig = sigf(g4[0] + b4.x);
        float fg = sigf(g4[1] + b4.y);
        float gg = tanh_fast(g4[2] + b4.z);
        float og = sigf(g4[3] + b4.w);
        float cn = fmaf(fg, cpre[it], ig * gg);
        float hn = og * tanh_fast(cn);
        hn_out[(size_t)m * H + hk] = hn;
        cn_out[(size_t)m * H + hk] = cn;
    }
}

// joint + argmax MFMA GEMM: logits = [enc | hn] @ [joint_W | C2]^T
__launch_bounds__(256, 2)
__global__ void joint_argmax(const float* __restrict__ enc,
                             const float* __restrict__ ws,
                             float* __restrict__ out) {
    // per buffer: A1[2048] A2[2048] B1[1536] B2[1536] halves = 14336 B
    __shared__ __align__(16) char smem[28672];
    const int tid = threadIdx.x, lane = tid & 63, w = tid >> 6;
    const int m0 = blockIdx.x * JBM;

    const f16* Jp1 = (const f16*)((const char*)ws + WS_JP_BYTE);
    const f16* Jp2 = Jp1 + JP_COUNT;
    const float* hn = out + NB;
    const float* jb2 = ws + WS_JB2;

    f16* base = (f16*)smem;

    f32x4 accM[3], accC[3];
    #pragma unroll
    for (int j = 0; j < 3; ++j) {
        accM[j] = (f32x4){0.f, 0.f, 0.f, 0.f};
        accC[j] = (f32x4){0.f, 0.f, 0.f, 0.f};
    }

    // A: one lane-linear 16B chunk per thread; B: linear 3KB copy
    auto stage = [&](int t, f16* A1, f16* A2, f16* B1, f16* B2) {
        const float* srcp = (t < 10) ? enc : hn;
        const int koff = (t % 10) * JBK;
        int row = (tid >> 6) * 16 + (tid & 15);
        int k0 = ((tid & 63) >> 4) * 8;
        const float* sp = srcp + (size_t)(m0 + row) * H + koff + k0;
        float4 v0 = *(const float4*)sp;
        float4 v1 = *(const float4*)(sp + 4);
        float e[8] = {v0.x, v0.y, v0.z, v0.w, v1.x, v1.y, v1.z, v1.w};
        f16x8 p1, p2;
        split8(e, p1, p2);
        *(f16x8*)(A1 + tid * 8) = p1;
        *(f16x8*)(A2 + tid * 8) = p2;
        if (tid < 192) {
            *(int4*)(B1 + tid * 8) = *(const int4*)(Jp1 + t * 1536 + tid * 8);
            *(int4*)(B2 + tid * 8) = *(const int4*)(Jp2 + t * 1536 + tid * 8);
        }
    };

    stage(0, base, base + 2048, base + 4096, base + 5632);
    __syncthreads();

    const int lo = lane * 8;
    int cur = 0;
    for (int t = 0; t < JKSTEPS; ++t) {
        if (t < JKSTEPS - 1) {
            f16* nb_ = base + (cur ^ 1) * 7168;
            stage(t + 1, nb_, nb_ + 2048, nb_ + 4096, nb_ + 5632);
        }
        f16* A1 = base + cur * 7168;
        f16* A2 = A1 + 2048;
        f16* B1 = A1 + 4096;
        f16* B2 = A1 + 5632;

        f16x8 a1 = *(const f16x8*)(A1 + w * 512 + lo);
        f16x8 a2 = *(const f16x8*)(A2 + w * 512 + lo);
        f16x8 b1[3], b2[3];
        #pragma unroll
        for (int nj = 0; nj < 3; ++nj) {
            b1[nj] = *(const f16x8*)(B1 + nj * 512 + lo);
            b2[nj] = *(const f16x8*)(B2 + nj * 512 + lo);
        }
        #pragma unroll
        for (int nj = 0; nj < 3; ++nj) {
            accM[nj] = __builtin_amdgcn_mfma_f32_16x16x32_f16(a1, b1[nj], accM[nj], 0, 0, 0);
            accC[nj] = __builtin_amdgcn_mfma_f32_16x16x32_f16(a1, b2[nj], accC[nj], 0, 0, 0);
            accC[nj] = __builtin_amdgcn_mfma_f32_16x16x32_f16(a2, b1[nj], accC[nj], 0, 0, 0);
        }
        __syncthreads();
        cur ^= 1;
    }

    // merge -> logits LDS [64][49] (stride 49: conflict-free column reads)
    float* lg = (float*)smem;
    const int wm = w * 16;
    #pragma unroll
    for (int nj = 0; nj < 3; ++nj) {
        int n = nj * 16 + (lane & 15);
        int mr = wm + (lane >> 4) * 4;
        #pragma unroll
        for (int q = 0; q < 4; ++q)
            lg[(mr + q) * 49 + n] = fmaf(accC[nj][q], 1.0f / 2048.0f, accM[nj][q]);
    }
    __syncthreads();

    // argmax per row (numpy: first max wins -> strict >)
    if (tid < JBM) {
        const float* row = lg + tid * 49;
        float best = row[0] + jb2[0];
        int bi = 0;
        #pragma unroll
        for (int v = 1; v < V; ++v) {
            float t2 = row[v] + jb2[v];
            if (t2 > best) { best = t2; bi = v; }
        }
        out[m0 + tid] = (float)bi;
    }
}

extern "C" void kernel_launch(void* const* d_in, const int* in_sizes, int n_in,
                              void* d_out, int out_size, void* d_ws, size_t ws_size,
                              hipStream_t stream) {
    const int*   x       = (const int*)  d_in[0];
    const float* enc     = (const float*)d_in[1];
    const float* h       = (const float*)d_in[2];
    const float* c       = (const float*)d_in[3];
    const float* embed_W = (const float*)d_in[4];
    const float* W_ih    = (const float*)d_in[5];
    const float* W_hh    = (const float*)d_in[6];
    const float* b_ih    = (const float*)d_in[7];
    const float* b_hh    = (const float*)d_in[8];
    const float* pred_W  = (const float*)d_in[9];
    const float* pred_b  = (const float*)d_in[10];
    const float* joint_W = (const float*)d_in[11];
    const float* joint_b = (const float*)d_in[12];
    float* out = (float*)d_out;
    float* ws  = (float*)d_ws;

    prep<<<PREP_NWG, 256, 0, stream>>>(embed_W, W_ih, b_ih, b_hh,
                                       pred_W, pred_b, joint_W, joint_b,
                                       W_hh, h, ws);
    lstm_gemm_fast<<<NWG, 256, 0, stream>>>(x, c, ws, out);
    joint_argmax<<<NB / JBM, 256, 0, stream>>>(enc, ws, out);
}